// Round 5
// baseline (44.201 us; speedup 1.0000x reference)
//
#include <hip/hip_runtime.h>

// PathDDPM q_sample, single streaming kernel, forced 16-deep load batch.
// x_t = sqrt(acp[t[b]]) * x_0 + sqrt(1-acp[t[b]]) * noise ; out = [x_t | noise]
// B=4096, L=2048, C=2 -> 16,777,216 fp32 per tensor, 4,194,304 float4.
// Schedule tables baked into __constant__ at compile time.

#define TSTEPS 1000

typedef float f4 __attribute__((ext_vector_type(4)));

constexpr double csqrt(double x) {
    double g = 1.0;
    for (int i = 0; i < 32; ++i) g = 0.5 * (g + x / g);
    return g;
}

struct Tables { float a[TSTEPS]; float s[TSTEPS]; };

constexpr Tables make_tables() {
    Tables tb{};
    const double step = (0.02 - 1e-4) / (double)(TSTEPS - 1);
    double run = 1.0;
    for (int i = 0; i < TSTEPS; ++i) {
        run *= (1.0 - (1e-4 + step * (double)i));
        tb.a[i] = (float)csqrt(run);
        tb.s[i] = (float)csqrt(1.0 - run);
    }
    return tb;
}

__constant__ Tables c_tab = make_tables();

// Each block owns a contiguous 2048-float4 (128 KB) span = exactly 2 rows
// (row = 1024 float4). grid 2048 x 256 covers all 4,194,304 float4.
__global__ void __launch_bounds__(256) ddpm_stream_kernel(
    const f4*  __restrict__ x0,
    const int* __restrict__ t,
    const f4*  __restrict__ nz,
    f4*        __restrict__ out_xt,
    f4*        __restrict__ out_nz)
{
    const int base = blockIdx.x * 2048 + threadIdx.x;

    // Two rows per block -> two scalar (a,s) pairs, pure SGPR path.
    const int t0 = t[2 * blockIdx.x];
    const int t1 = t[2 * blockIdx.x + 1];
    const float a0 = c_tab.a[t0], sc0 = c_tab.s[t0];
    const float a1 = c_tab.a[t1], sc1 = c_tab.s[t1];

    // Phase 1: issue ALL 16 loads, interleaved (x[k],n[k]) so that the k-th
    // store pair can drain at vmcnt(14-2k) while later loads stay in flight.
    f4 x[8], n[8];
    #pragma unroll
    for (int k = 0; k < 8; ++k) {
        x[k] = x0[base + k * 256];
        n[k] = nz[base + k * 256];
    }
    // Hard fence: forbid the scheduler from sinking loads into the store
    // phase (which is how R4's batch collapsed back to VGPR=32 / ~2 deep).
    __builtin_amdgcn_sched_barrier(0);

    // Phase 2: fma + nontemporal stores (outputs never re-read; keep L3
    // free for the replay-resident inputs).
    #pragma unroll
    for (int k = 0; k < 8; ++k) {
        const float a = (k < 4) ? a0 : a1;
        const float s = (k < 4) ? sc0 : sc1;
        f4 o;
        o.x = fmaf(a, x[k].x, s * n[k].x);
        o.y = fmaf(a, x[k].y, s * n[k].y);
        o.z = fmaf(a, x[k].z, s * n[k].z);
        o.w = fmaf(a, x[k].w, s * n[k].w);
        __builtin_nontemporal_store(o,    &out_xt[base + k * 256]);
        __builtin_nontemporal_store(n[k], &out_nz[base + k * 256]);
    }
}

extern "C" void kernel_launch(void* const* d_in, const int* in_sizes, int n_in,
                              void* d_out, int out_size, void* d_ws, size_t ws_size,
                              hipStream_t stream) {
    const float* x0 = (const float*)d_in[0];   // [B, L, 2] fp32
    const int*   t  = (const int*)  d_in[1];   // [B] int32
    const float* nz = (const float*)d_in[2];   // [B, L, 2] fp32
    float* out = (float*)d_out;                // [x_t | noise] concatenated
    const int n = 4096 * 2048 * 2;             // elements per tensor

    ddpm_stream_kernel<<<2048, 256, 0, stream>>>(
        (const f4*)x0, t, (const f4*)nz,
        (f4*)out, (f4*)(out + n));
}